// Round 3
// baseline (6126.618 us; speedup 1.0000x reference)
//
#include <hip/hip_runtime.h>

#define HW 4096
#define NC 512
#define NP 100
#define NB 16
#define GAMMA 10.0f

// ws layout (floats):
// [0, 51200)        Wp (normalized proxies, [c][p])
// [51200, 51328)    accums: [0]=num_pos,[1]=num_neg,[2]=sum_t,[3]=reg_sum,[8..108)=grm

__global__ void k_norm_proxies(const float* __restrict__ pp, float* __restrict__ Wp) {
    int p = blockIdx.x;      // 0..99
    int t = threadIdx.x;     // 0..63 (one wave)
    float s = 0.f;
    for (int c = t; c < NC; c += 64) { float v = pp[c * NP + p]; s += v * v; }
    #pragma unroll
    for (int off = 32; off > 0; off >>= 1) s += __shfl_down(s, off);
    s = __shfl(s, 0);
    float inv = 1.0f / sqrtf(s + 1e-12f);
    for (int c = t; c < NC; c += 64) Wp[c * NP + p] = pp[c * NP + p] * inv;
}

// loss_reg via identity: sum_{p!=q} (Wp^T Wp)[p,q] = sum_c (sum_p w_cp)^2 - sum_{c,p} w_cp^2
__global__ void k_reg2(const float* __restrict__ Wp, float* __restrict__ accums) {
    __shared__ float wsum[8];
    int tid = threadIdx.x;           // 512 threads, one per c
    const float4* r = reinterpret_cast<const float4*>(Wp + tid * NP);
    float s = 0.f, ss = 0.f;
    #pragma unroll
    for (int j = 0; j < 25; ++j) {
        float4 v = r[j];
        s  += v.x + v.y + v.z + v.w;
        ss += v.x * v.x + v.y * v.y + v.z * v.z + v.w * v.w;
    }
    float contrib = s * s - ss;
    #pragma unroll
    for (int off = 32; off > 0; off >>= 1) contrib += __shfl_xor(contrib, off);
    if ((tid & 63) == 0) wsum[tid >> 6] = contrib;
    __syncthreads();
    if (tid == 0) {
        float tot = 0.f;
        #pragma unroll
        for (int i = 0; i < 8; ++i) tot += wsum[i];
        accums[3] = tot;
    }
}

__device__ __forceinline__ void proc8(const float (&xr)[8], const float (&gr)[8],
                                      const float* wbase, float (&acc)[NP],
                                      float& sxx, float& sgg, float& sxg) {
    #pragma unroll
    for (int i = 0; i < 8; ++i) {
        float xv = xr[i], gv = gr[i];
        sxx = fmaf(xv, xv, sxx);
        sgg = fmaf(gv, gv, sgg);
        sxg = fmaf(xv, gv, sxg);
        const float* wrow = wbase + i * NP;
        #pragma unroll
        for (int q = 0; q < 25; ++q) {
            float4 w4 = *reinterpret_cast<const float4*>(wrow + 4 * q);
            acc[4*q+0] = fmaf(xv, w4.x, acc[4*q+0]);
            acc[4*q+1] = fmaf(xv, w4.y, acc[4*q+1]);
            acc[4*q+2] = fmaf(xv, w4.z, acc[4*q+2]);
            acc[4*q+3] = fmaf(xv, w4.w, acc[4*q+3]);
        }
    }
}

// 256 threads/block: threads 0-127 = c[0,256) ("half 0"), 128-255 = c[256,512) ("half 1"),
// same 128 points. Partial acc combined via LDS after the main loop. 2 waves/SIMD occupancy.
__global__ __launch_bounds__(256, 2) void k_main(
        const float* __restrict__ x, const float* __restrict__ xgt,
        const float* __restrict__ t, const float* __restrict__ ha,
        const float* __restrict__ Wp, float* __restrict__ accums) {
    // wlds doubles as: [2][6400] Wp-segment staging (main loop), then [128]x(stride 101)
    // acc-exchange buffer (stride 101: bank=(5*lane+p)%32, conflict-free).
    __shared__ __align__(16) float wlds[12928];   // 51.7 KB
    __shared__ float scx[128 * 4];
    __shared__ float grmLDS[NP];
    __shared__ float scal[3];

    int tid  = threadIdx.x;
    int half = tid >> 7;            // 0 or 1
    int hidx = tid & 127;           // point index within block
    int point = blockIdx.x * 128 + hidx;   // 65536 points
    int b = point >> 12;            // 4096 points per b; blocks never straddle b
    int n = point & (HW - 1);

    if (tid < NP) grmLDS[tid] = 0.f;
    if (tid < 3)  scal[tid]  = 0.f;

    // t-flag (half 0 only; used only in epilogue)
    float tf = 0.f;
    if (half == 0) {
        int h = n >> 6, w = n & 63;
        const float* tb = t + (size_t)b * (256 * 256) + (h * 4) * 256 + w * 4;
        float ts = 0.f;
        #pragma unroll
        for (int i = 0; i < 4; ++i) {
            float4 v = *reinterpret_cast<const float4*>(tb + i * 256);
            ts += v.x + v.y + v.z + v.w;
        }
        tf = (ts * (1.0f / 16.0f) > 0.02f) ? 1.0f : 0.0f;
    }

    const float* xp = x   + (size_t)b * (NC * HW) + (size_t)(half * 256) * HW + n;
    const float* gp = xgt + (size_t)b * (NC * HW) + (size_t)(half * 256) * HW + n;

    float acc[NP];
    #pragma unroll
    for (int p = 0; p < NP; ++p) acc[p] = 0.f;
    float sxx = 0.f, sgg = 0.f, sxg = 0.f;

    // 32 chunks of 8 c's per thread (256 c per half), register double-buffered prefetch
    float xa[8], ga[8], xb[8], gb[8];
    #pragma unroll
    for (int i = 0; i < 8; ++i) { xa[i] = xp[(size_t)i * HW]; ga[i] = gp[(size_t)i * HW]; }

    float* wbuf = wlds + half * 6400;
    float4* wl4 = reinterpret_cast<float4*>(wbuf);

    for (int seg = 0; seg < 4; ++seg) {
        __syncthreads();   // previous segment fully consumed
        const float4* ws4 = reinterpret_cast<const float4*>(Wp + (half * 256 + seg * 64) * NP);
        #pragma unroll 4
        for (int j = 0; j < 12; ++j) wl4[hidx + j * 128] = ws4[hidx + j * 128];
        if (hidx < 64) wl4[1536 + hidx] = ws4[1536 + hidx];
        __syncthreads();

        #pragma unroll
        for (int cc = 0; cc < 8; cc += 2) {
            int k = seg * 8 + cc;            // 0..30
            {   // prefetch chunk k+1 (always valid: k+1 <= 31)
                const float* xc = xp + (size_t)(k + 1) * 8 * HW;
                const float* gc = gp + (size_t)(k + 1) * 8 * HW;
                #pragma unroll
                for (int i = 0; i < 8; ++i) { xb[i] = xc[(size_t)i * HW]; gb[i] = gc[(size_t)i * HW]; }
            }
            proc8(xa, ga, wbuf + (cc * 8) * NP, acc, sxx, sgg, sxg);
            if (k + 2 < 32) {
                const float* xc = xp + (size_t)(k + 2) * 8 * HW;
                const float* gc = gp + (size_t)(k + 2) * 8 * HW;
                #pragma unroll
                for (int i = 0; i < 8; ++i) { xa[i] = xc[(size_t)i * HW]; ga[i] = gc[(size_t)i * HW]; }
            }
            proc8(xb, gb, wbuf + ((cc + 1) * 8) * NP, acc, sxx, sgg, sxg);
        }
    }

    // ---- combine the two c-halves through LDS ----
    __syncthreads();                 // everyone done with wlds-as-Wp
    if (half == 1) {
        scx[hidx * 4 + 0] = sxx;
        scx[hidx * 4 + 1] = sgg;
        scx[hidx * 4 + 2] = sxg;
        float* dst = wlds + hidx * 101;
        #pragma unroll
        for (int p = 0; p < NP; ++p) dst[p] = acc[p];
    }
    __syncthreads();

    if (half == 0) {
        sxx += scx[hidx * 4 + 0];
        sgg += scx[hidx * 4 + 1];
        sxg += scx[hidx * 4 + 2];
        const float* src = wlds + hidx * 101;
        #pragma unroll
        for (int p = 0; p < NP; ++p) acc[p] += src[p];

        // epilogue: softmax over P, similarities, contributions
        float invx = 1.0f / sqrtf(sxx + 1e-12f);
        float m = -1e30f;
        #pragma unroll
        for (int p = 0; p < NP; ++p) { acc[p] *= invx; m = fmaxf(m, acc[p]); }
        float s = 0.f, sf = 0.f;
        #pragma unroll
        for (int p = 0; p < NP; ++p) {
            float ev = __expf(GAMMA * (acc[p] - m));
            s += ev; sf = fmaf(ev, acc[p], sf);
            acc[p] = ev;
        }
        float Sim   = sf / s;
        float invg  = 1.0f / sqrtf(sgg + 1e-12f);
        float cosgt = sxg * invx * invg;

        int lane = tid & 63;
        float v0 = (1.0f - Sim)   * (1.0f - tf);
        float v1 = (1.0f - cosgt) * tf;
        float v2 = tf;
        #pragma unroll
        for (int off = 32; off > 0; off >>= 1) {
            v0 += __shfl_xor(v0, off);
            v1 += __shfl_xor(v1, off);
            v2 += __shfl_xor(v2, off);
        }
        if (lane == 0) {
            atomicAdd(&scal[0], v0);
            atomicAdd(&scal[1], v1);
            atomicAdd(&scal[2], v2);
        }
        float winv = (1.0f - ha[b]) / s;
        #pragma unroll
        for (int p = 0; p < NP; ++p) {
            float g = acc[p] * winv;
            #pragma unroll
            for (int off = 32; off > 0; off >>= 1) g += __shfl_xor(g, off);
            if (lane == 0) atomicAdd(&grmLDS[p], g);
        }
    }
    __syncthreads();
    if (tid < NP) atomicAdd(&accums[8 + tid], grmLDS[tid]);
    if (tid < 3)  atomicAdd(&accums[tid], scal[tid]);
}

__global__ void k_final(const float* __restrict__ accums, const float* __restrict__ ha,
                        const float* __restrict__ gr, float* __restrict__ out) {
    __shared__ float red;
    int t = threadIdx.x;    // 128
    if (t == 0) red = 0.f;
    __syncthreads();
    float S = 0.f;
    #pragma unroll
    for (int b2 = 0; b2 < NB; ++b2) S += 1.0f - ha[b2];
    float contrib = 0.f;
    if (t < NP) {
        float g = accums[8 + t] / (4096.0f * (S + 1e-12f));
        contrib = fabsf(g - gr[t]);
    }
    atomicAdd(&red, contrib);
    __syncthreads();
    if (t == 0) {
        float num_pos = accums[0], num_neg = accums[1], sum_t = accums[2], reg = accums[3];
        float den_pos = (float)(NB * HW) - sum_t;
        float loss_pos = num_pos / (den_pos + 1e-12f);
        float loss_neg = num_neg / (sum_t + 1e-12f);
        float loss_reg = reg / (float)(NP * NP);
        float loss_glob = red / (float)NP;
        out[0] = loss_pos + loss_neg + 0.1f * loss_reg + loss_glob;
    }
}

extern "C" void kernel_launch(void* const* d_in, const int* in_sizes, int n_in,
                              void* d_out, int out_size, void* d_ws, size_t ws_size,
                              hipStream_t stream) {
    const float* x   = (const float*)d_in[0];
    const float* xgt = (const float*)d_in[1];
    const float* t   = (const float*)d_in[2];
    // d_in[3] = ds (int scalar, fixed = 4)
    const float* ha  = (const float*)d_in[4];
    const float* pp  = (const float*)d_in[5];
    const float* gr  = (const float*)d_in[6];
    float* out = (float*)d_out;

    float* Wp     = (float*)d_ws;
    float* accums = Wp + 51200;

    hipMemsetAsync(accums, 0, 128 * sizeof(float), stream);
    k_norm_proxies<<<100, 64, 0, stream>>>(pp, Wp);
    k_reg2<<<1, 512, 0, stream>>>(Wp, accums);
    k_main<<<512, 256, 0, stream>>>(x, xgt, t, ha, Wp, accums);
    k_final<<<1, 128, 0, stream>>>(accums, ha, gr, out);
}

// Round 5
// 6087.181 us; speedup vs baseline: 1.0065x; 1.0065x over previous
//
#include <hip/hip_runtime.h>

#define HW 4096
#define NC 512
#define NP 100
#define NB 16
#define GAMMA 10.0f

// ws layout (floats):
// [0, 51200)        Wp (normalized proxies, [c][p])
// [51200, 51328)    accums: [0]=num_pos,[1]=num_neg,[2]=sum_t,[3]=reg_sum,[8..108)=grm

__global__ void k_norm_proxies(const float* __restrict__ pp, float* __restrict__ Wp) {
    int p = blockIdx.x;      // 0..99
    int t = threadIdx.x;     // 0..63 (one wave)
    float s = 0.f;
    for (int c = t; c < NC; c += 64) { float v = pp[c * NP + p]; s += v * v; }
    #pragma unroll
    for (int off = 32; off > 0; off >>= 1) s += __shfl_down(s, off);
    s = __shfl(s, 0);
    float inv = 1.0f / sqrtf(s + 1e-12f);
    for (int c = t; c < NC; c += 64) Wp[c * NP + p] = pp[c * NP + p] * inv;
}

// loss_reg via identity: sum_{p!=q} (Wp^T Wp)[p,q] = sum_c (sum_p w_cp)^2 - sum_{c,p} w_cp^2
__global__ void k_reg2(const float* __restrict__ Wp, float* __restrict__ accums) {
    __shared__ float wsum[8];
    int tid = threadIdx.x;           // 512 threads, one per c
    const float4* r = reinterpret_cast<const float4*>(Wp + tid * NP);
    float s = 0.f, ss = 0.f;
    #pragma unroll
    for (int j = 0; j < 25; ++j) {
        float4 v = r[j];
        s  += v.x + v.y + v.z + v.w;
        ss += v.x * v.x + v.y * v.y + v.z * v.z + v.w * v.w;
    }
    float contrib = s * s - ss;
    #pragma unroll
    for (int off = 32; off > 0; off >>= 1) contrib += __shfl_xor(contrib, off);
    if ((tid & 63) == 0) wsum[tid >> 6] = contrib;
    __syncthreads();
    if (tid == 0) {
        float tot = 0.f;
        #pragma unroll
        for (int i = 0; i < 8; ++i) tot += wsum[i];
        accums[3] = tot;
    }
}

__device__ __forceinline__ void proc8(const float (&xr)[8], const float (&gr)[8],
                                      const float* wbase, float (&acc)[NP],
                                      float& sxx, float& sgg, float& sxg) {
    #pragma unroll
    for (int i = 0; i < 8; ++i) {
        float xv = xr[i], gv = gr[i];
        sxx = fmaf(xv, xv, sxx);
        sgg = fmaf(gv, gv, sgg);
        sxg = fmaf(xv, gv, sxg);
        const float* wrow = wbase + i * NP;
        #pragma unroll
        for (int q = 0; q < 25; ++q) {
            float4 w4 = *reinterpret_cast<const float4*>(wrow + 4 * q);
            acc[4*q+0] = fmaf(xv, w4.x, acc[4*q+0]);
            acc[4*q+1] = fmaf(xv, w4.y, acc[4*q+1]);
            acc[4*q+2] = fmaf(xv, w4.z, acc[4*q+2]);
            acc[4*q+3] = fmaf(xv, w4.w, acc[4*q+3]);
        }
    }
}

// 256 threads/block: threads 0-127 = c[0,256) ("half 0"), 128-255 = c[256,512) ("half 1"),
// same 128 points. Partial acc combined via LDS after the main loop.
// amdgpu_waves_per_eu(2,2): pin regalloc to the 2-waves/SIMD budget (256 VGPR) —
// round-3 profile showed the default heuristic chose 128 VGPR and spilled acc[100]
// to scratch (11.8 GB spill writes, VALUBusy 0.9%, 6 ms).
__global__ __launch_bounds__(256)
__attribute__((amdgpu_waves_per_eu(2, 2)))
void k_main(
        const float* __restrict__ x, const float* __restrict__ xgt,
        const float* __restrict__ t, const float* __restrict__ ha,
        const float* __restrict__ Wp, float* __restrict__ accums) {
    // wlds doubles as: [2][6400] Wp-segment staging (main loop), then [128]x(stride 101)
    // acc-exchange buffer (stride 101: bank=(5*lane+p)%32, conflict-free).
    __shared__ __align__(16) float wlds[12928];   // 51.7 KB
    __shared__ float scx[128 * 4];
    __shared__ float grmLDS[NP];
    __shared__ float scal[3];

    int tid  = threadIdx.x;
    int half = tid >> 7;            // 0 or 1
    int hidx = tid & 127;           // point index within block
    int point = blockIdx.x * 128 + hidx;   // 65536 points
    int b = point >> 12;            // 4096 points per b; blocks never straddle b
    int n = point & (HW - 1);

    if (tid < NP) grmLDS[tid] = 0.f;
    if (tid < 3)  scal[tid]  = 0.f;

    // t-flag (half 0 only; used only in epilogue)
    float tf = 0.f;
    if (half == 0) {
        int h = n >> 6, w = n & 63;
        const float* tb = t + (size_t)b * (256 * 256) + (h * 4) * 256 + w * 4;
        float ts = 0.f;
        #pragma unroll
        for (int i = 0; i < 4; ++i) {
            float4 v = *reinterpret_cast<const float4*>(tb + i * 256);
            ts += v.x + v.y + v.z + v.w;
        }
        tf = (ts * (1.0f / 16.0f) > 0.02f) ? 1.0f : 0.0f;
    }

    const float* xp = x   + (size_t)b * (NC * HW) + (size_t)(half * 256) * HW + n;
    const float* gp = xgt + (size_t)b * (NC * HW) + (size_t)(half * 256) * HW + n;

    float acc[NP];
    #pragma unroll
    for (int p = 0; p < NP; ++p) acc[p] = 0.f;
    float sxx = 0.f, sgg = 0.f, sxg = 0.f;

    // 32 chunks of 8 c's per thread (256 c per half), register double-buffered prefetch
    float xa[8], ga[8], xb[8], gb[8];
    #pragma unroll
    for (int i = 0; i < 8; ++i) { xa[i] = xp[(size_t)i * HW]; ga[i] = gp[(size_t)i * HW]; }

    float* wbuf = wlds + half * 6400;
    float4* wl4 = reinterpret_cast<float4*>(wbuf);

    for (int seg = 0; seg < 4; ++seg) {
        __syncthreads();   // previous segment fully consumed
        const float4* ws4 = reinterpret_cast<const float4*>(Wp + (half * 256 + seg * 64) * NP);
        #pragma unroll 4
        for (int j = 0; j < 12; ++j) wl4[hidx + j * 128] = ws4[hidx + j * 128];
        if (hidx < 64) wl4[1536 + hidx] = ws4[1536 + hidx];
        __syncthreads();

        #pragma unroll
        for (int cc = 0; cc < 8; cc += 2) {
            int k = seg * 8 + cc;            // 0..30
            {   // prefetch chunk k+1 (always valid: k+1 <= 31)
                const float* xc = xp + (size_t)(k + 1) * 8 * HW;
                const float* gc = gp + (size_t)(k + 1) * 8 * HW;
                #pragma unroll
                for (int i = 0; i < 8; ++i) { xb[i] = xc[(size_t)i * HW]; gb[i] = gc[(size_t)i * HW]; }
            }
            proc8(xa, ga, wbuf + (cc * 8) * NP, acc, sxx, sgg, sxg);
            if (k + 2 < 32) {
                const float* xc = xp + (size_t)(k + 2) * 8 * HW;
                const float* gc = gp + (size_t)(k + 2) * 8 * HW;
                #pragma unroll
                for (int i = 0; i < 8; ++i) { xa[i] = xc[(size_t)i * HW]; ga[i] = gc[(size_t)i * HW]; }
            }
            proc8(xb, gb, wbuf + ((cc + 1) * 8) * NP, acc, sxx, sgg, sxg);
        }
    }

    // ---- combine the two c-halves through LDS ----
    __syncthreads();                 // everyone done with wlds-as-Wp
    if (half == 1) {
        scx[hidx * 4 + 0] = sxx;
        scx[hidx * 4 + 1] = sgg;
        scx[hidx * 4 + 2] = sxg;
        float* dst = wlds + hidx * 101;
        #pragma unroll
        for (int p = 0; p < NP; ++p) dst[p] = acc[p];
    }
    __syncthreads();

    if (half == 0) {
        sxx += scx[hidx * 4 + 0];
        sgg += scx[hidx * 4 + 1];
        sxg += scx[hidx * 4 + 2];
        const float* src = wlds + hidx * 101;
        #pragma unroll
        for (int p = 0; p < NP; ++p) acc[p] += src[p];

        // epilogue: softmax over P, similarities, contributions
        float invx = 1.0f / sqrtf(sxx + 1e-12f);
        float m = -1e30f;
        #pragma unroll
        for (int p = 0; p < NP; ++p) { acc[p] *= invx; m = fmaxf(m, acc[p]); }
        float s = 0.f, sf = 0.f;
        #pragma unroll
        for (int p = 0; p < NP; ++p) {
            float ev = __expf(GAMMA * (acc[p] - m));
            s += ev; sf = fmaf(ev, acc[p], sf);
            acc[p] = ev;
        }
        float Sim   = sf / s;
        float invg  = 1.0f / sqrtf(sgg + 1e-12f);
        float cosgt = sxg * invx * invg;

        int lane = tid & 63;
        float v0 = (1.0f - Sim)   * (1.0f - tf);
        float v1 = (1.0f - cosgt) * tf;
        float v2 = tf;
        #pragma unroll
        for (int off = 32; off > 0; off >>= 1) {
            v0 += __shfl_xor(v0, off);
            v1 += __shfl_xor(v1, off);
            v2 += __shfl_xor(v2, off);
        }
        if (lane == 0) {
            atomicAdd(&scal[0], v0);
            atomicAdd(&scal[1], v1);
            atomicAdd(&scal[2], v2);
        }
        float winv = (1.0f - ha[b]) / s;
        #pragma unroll
        for (int p = 0; p < NP; ++p) {
            float g = acc[p] * winv;
            #pragma unroll
            for (int off = 32; off > 0; off >>= 1) g += __shfl_xor(g, off);
            if (lane == 0) atomicAdd(&grmLDS[p], g);
        }
    }
    __syncthreads();
    if (tid < NP) atomicAdd(&accums[8 + tid], grmLDS[tid]);
    if (tid < 3)  atomicAdd(&accums[tid], scal[tid]);
}

__global__ void k_final(const float* __restrict__ accums, const float* __restrict__ ha,
                        const float* __restrict__ gr, float* __restrict__ out) {
    __shared__ float red;
    int t = threadIdx.x;    // 128
    if (t == 0) red = 0.f;
    __syncthreads();
    float S = 0.f;
    #pragma unroll
    for (int b2 = 0; b2 < NB; ++b2) S += 1.0f - ha[b2];
    float contrib = 0.f;
    if (t < NP) {
        float g = accums[8 + t] / (4096.0f * (S + 1e-12f));
        contrib = fabsf(g - gr[t]);
    }
    atomicAdd(&red, contrib);
    __syncthreads();
    if (t == 0) {
        float num_pos = accums[0], num_neg = accums[1], sum_t = accums[2], reg = accums[3];
        float den_pos = (float)(NB * HW) - sum_t;
        float loss_pos = num_pos / (den_pos + 1e-12f);
        float loss_neg = num_neg / (sum_t + 1e-12f);
        float loss_reg = reg / (float)(NP * NP);
        float loss_glob = red / (float)NP;
        out[0] = loss_pos + loss_neg + 0.1f * loss_reg + loss_glob;
    }
}

extern "C" void kernel_launch(void* const* d_in, const int* in_sizes, int n_in,
                              void* d_out, int out_size, void* d_ws, size_t ws_size,
                              hipStream_t stream) {
    const float* x   = (const float*)d_in[0];
    const float* xgt = (const float*)d_in[1];
    const float* t   = (const float*)d_in[2];
    // d_in[3] = ds (int scalar, fixed = 4)
    const float* ha  = (const float*)d_in[4];
    const float* pp  = (const float*)d_in[5];
    const float* gr  = (const float*)d_in[6];
    float* out = (float*)d_out;

    float* Wp     = (float*)d_ws;
    float* accums = Wp + 51200;

    hipMemsetAsync(accums, 0, 128 * sizeof(float), stream);
    k_norm_proxies<<<100, 64, 0, stream>>>(pp, Wp);
    k_reg2<<<1, 512, 0, stream>>>(Wp, accums);
    k_main<<<512, 256, 0, stream>>>(x, xgt, t, ha, Wp, accums);
    k_final<<<1, 128, 0, stream>>>(accums, ha, gr, out);
}